// Round 1
// baseline (4756.979 us; speedup 1.0000x reference)
//
#include <hip/hip_runtime.h>

#define T_ 256
#define B_ 128
#define I_ 1024
#define H_ 1024
#define G_ 4096   // 4*H
#define BH (B_*H_)   // 131072
#define TB (T_*B_)   // 32768

typedef float f32x4 __attribute__((ext_vector_type(4)));
typedef short bf16x8 __attribute__((ext_vector_type(8)));

__device__ inline unsigned short f2bf(float f) {
    union { float f; unsigned int u; } v; v.f = f;
    unsigned int u = v.u;
    unsigned int r = (u + 0x7fffu + ((u >> 16) & 1u)) >> 16;
    return (unsigned short)r;
}
__device__ inline float bf2f(unsigned short s) {
    union { unsigned int u; float f; } v; v.u = ((unsigned int)s) << 16;
    return v.f;
}
__device__ inline float sigmoidf_(float x) { return 1.0f / (1.0f + __expf(-x)); }
__device__ inline float tanhf_(float x) {
    x = fminf(15.0f, fmaxf(-15.0f, x));
    float e = __expf(2.0f * x);
    return (e - 1.0f) / (e + 1.0f);
}

// ---------------- convert fp32 -> bf16 (vectorized) ----------------
__global__ void cvt_kernel(const float* __restrict__ src, unsigned short* __restrict__ dst, int n) {
    int i = (blockIdx.x * blockDim.x + threadIdx.x) * 4;
    int stride = gridDim.x * blockDim.x * 4;
    for (; i < n; i += stride) {
        float4 v = *reinterpret_cast<const float4*>(src + i);
        ushort4 o;
        o.x = f2bf(v.x); o.y = f2bf(v.y); o.z = f2bf(v.z); o.w = f2bf(v.w);
        *reinterpret_cast<ushort4*>(dst + i) = o;
    }
}

__global__ void bias_kernel(const float* __restrict__ a, const float* __restrict__ b, float* __restrict__ out) {
    int i = blockIdx.x * blockDim.x + threadIdx.x;
    if (i < G_) out[i] = a[i] + b[i];
}

// ---------------- pre-GEMM: gates_x = x @ Wih^T + bias  (bf16 out) ----------------
// M = 32768, N = 4096, K = 1024. Both operands row-major with K contiguous.
// Block: 256 thr (4 waves), tile 128x128; wave quadrant 64x64 (4x4 MFMA frags).
__global__ __launch_bounds__(256) void pregemm(
    const unsigned short* __restrict__ xb,   // [32768][1024] bf16
    const unsigned short* __restrict__ wih,  // [4096][1024] bf16
    const float* __restrict__ bias,          // [4096]
    unsigned short* __restrict__ gx)         // [32768][4096] bf16
{
    // XCD-aware swizzle: consecutive blocks on one XCD share the same N-panel.
    int wgid = (blockIdx.x & 7) * 1024 + (blockIdx.x >> 3);   // 8192 = 8*1024, bijective
    int mg = wgid & 255;    // 256 M-groups
    int ng = wgid >> 8;     // 32 N-groups
    int m0 = mg * 128, n0 = ng * 128;
    int tid = threadIdx.x;
    int w = tid >> 6, l = tid & 63;
    int qm = (w >> 1) * 64, qn = (w & 1) * 64;
    int lr = l & 15, lk = (l >> 4) * 8, lq = l >> 4;

    const unsigned short* ap = xb  + (size_t)(m0 + qm + lr) * I_ + lk;
    const unsigned short* bp = wih + (size_t)(n0 + qn + lr) * I_ + lk;

    f32x4 acc[4][4] = {};
    #pragma unroll 4
    for (int kk = 0; kk < 32; ++kk) {
        bf16x8 a[4], b[4];
        #pragma unroll
        for (int mt = 0; mt < 4; ++mt)
            a[mt] = *reinterpret_cast<const bf16x8*>(ap + (size_t)mt * 16 * I_ + kk * 32);
        #pragma unroll
        for (int nt = 0; nt < 4; ++nt)
            b[nt] = *reinterpret_cast<const bf16x8*>(bp + (size_t)nt * 16 * I_ + kk * 32);
        #pragma unroll
        for (int mt = 0; mt < 4; ++mt)
            #pragma unroll
            for (int nt = 0; nt < 4; ++nt)
                acc[mt][nt] = __builtin_amdgcn_mfma_f32_16x16x32_bf16(a[mt], b[nt], acc[mt][nt], 0, 0, 0);
    }
    // C/D layout (m89-verified): col = lane&15, row = (lane>>4)*4 + reg
    #pragma unroll
    for (int mt = 0; mt < 4; ++mt) {
        #pragma unroll
        for (int nt = 0; nt < 4; ++nt) {
            #pragma unroll
            for (int r = 0; r < 4; ++r) {
                int m = m0 + qm + mt * 16 + lq * 4 + r;
                int n = n0 + qn + nt * 16 + lr;
                gx[(size_t)m * G_ + n] = f2bf(acc[mt][nt][r] + bias[n]);
            }
        }
    }
}

// ---------------- one LSTM time step ----------------
// Block: [32 batch rows x 16 h-cols]; wave w computes gate chunk w (i/f/g/o)
// gates[32x16] = h[32x1024] @ Whh[w*1024+n0 .. +16][1024]^T, then fused elementwise.
__global__ __launch_bounds__(256) void lstm_step(
    const unsigned short* __restrict__ hprev, // [128][1024] bf16
    const unsigned short* __restrict__ whh,   // [4096][1024] bf16
    const unsigned short* __restrict__ gxt,   // [128][4096] bf16 (this step's slice)
    float* __restrict__ c,                    // [128][1024] fp32, in/out
    float* __restrict__ yst,                  // [128][1024] fp32 out
    unsigned short* __restrict__ hnext)       // [128][1024] bf16 out
{
    __shared__ float lds_g[4][32][16];
    int mg = blockIdx.x >> 6;   // 4 batch groups of 32
    int ng = blockIdx.x & 63;   // 64 col groups of 16
    int tid = threadIdx.x;
    int w = tid >> 6, l = tid & 63;
    int lr = l & 15, lk = (l >> 4) * 8, lq = l >> 4;
    int m0 = mg * 32, n0 = ng * 16;

    const unsigned short* ap = hprev + (size_t)(m0 + lr) * H_ + lk;
    const unsigned short* bp = whh   + (size_t)(w * 1024 + n0 + lr) * H_ + lk;

    f32x4 acc0 = {}, acc1 = {};
    #pragma unroll 8
    for (int kk = 0; kk < 32; ++kk) {
        bf16x8 a0 = *reinterpret_cast<const bf16x8*>(ap + kk * 32);
        bf16x8 a1 = *reinterpret_cast<const bf16x8*>(ap + (size_t)16 * H_ + kk * 32);
        bf16x8 bb = *reinterpret_cast<const bf16x8*>(bp + kk * 32);
        acc0 = __builtin_amdgcn_mfma_f32_16x16x32_bf16(a0, bb, acc0, 0, 0, 0);
        acc1 = __builtin_amdgcn_mfma_f32_16x16x32_bf16(a1, bb, acc1, 0, 0, 0);
    }
    #pragma unroll
    for (int r = 0; r < 4; ++r) {
        lds_g[w][lq * 4 + r][lr]      = acc0[r];
        lds_g[w][16 + lq * 4 + r][lr] = acc1[r];
    }
    __syncthreads();

    #pragma unroll
    for (int e = 0; e < 2; ++e) {
        int idx = tid + e * 256;
        int row = idx >> 4, col = idx & 15;
        size_t gb = (size_t)(m0 + row) * G_ + n0 + col;
        float gi = lds_g[0][row][col] + bf2f(gxt[gb]);
        float gf = lds_g[1][row][col] + bf2f(gxt[gb + 1024]);
        float gg = lds_g[2][row][col] + bf2f(gxt[gb + 2048]);
        float go = lds_g[3][row][col] + bf2f(gxt[gb + 3072]);
        float iv = sigmoidf_(gi);
        float fv = sigmoidf_(gf);
        float gv = tanhf_(gg);
        float ov = sigmoidf_(go);
        size_t ho = (size_t)(m0 + row) * H_ + n0 + col;
        float cn = fv * c[ho] + iv * gv;
        c[ho] = cn;
        float hn = ov * tanhf_(cn);
        yst[ho] = hn;
        hnext[ho] = f2bf(hn);
    }
}

extern "C" void kernel_launch(void* const* d_in, const int* in_sizes, int n_in,
                              void* d_out, int out_size, void* d_ws, size_t ws_size,
                              hipStream_t stream)
{
    const float* x   = (const float*)d_in[0];
    const float* h0  = (const float*)d_in[1];
    const float* c0  = (const float*)d_in[2];
    const float* Wih = (const float*)d_in[3];
    const float* Whh = (const float*)d_in[4];
    const float* bih = (const float*)d_in[5];
    const float* bhh = (const float*)d_in[6];

    // workspace layout (bytes)
    char* ws = (char*)d_ws;
    unsigned short* gx   = (unsigned short*)(ws);                 // 256 MB: gates_x bf16 [32768][4096]
    unsigned short* xb   = (unsigned short*)(ws + 268435456);     //  64 MB: x bf16
    unsigned short* wihb = (unsigned short*)(ws + 335544320);     //   8 MB: Wih bf16
    unsigned short* whhb = (unsigned short*)(ws + 343932928);     //   8 MB: Whh bf16
    unsigned short* hbuf = (unsigned short*)(ws + 352321536);     // 512 KB: h double buffer bf16
    float*          bias = (float*)(ws + 352845824);              //  16 KB: b_ih + b_hh

    float* out = (float*)d_out;
    float* ys = out;                           // [256][128][1024]
    float* hT = out + (size_t)TB * H_;         // [128][1024]
    float* cT = hT + BH;                       // [128][1024] -- used as running c

    cvt_kernel<<<2048, 256, 0, stream>>>(x,   xb,   TB * I_);
    cvt_kernel<<<512,  256, 0, stream>>>(Wih, wihb, G_ * I_);
    cvt_kernel<<<512,  256, 0, stream>>>(Whh, whhb, G_ * H_);
    cvt_kernel<<<128,  256, 0, stream>>>(h0,  hbuf, BH);
    bias_kernel<<<16, 256, 0, stream>>>(bih, bhh, bias);
    hipMemcpyAsync(cT, c0, (size_t)BH * sizeof(float), hipMemcpyDeviceToDevice, stream);

    pregemm<<<8192, 256, 0, stream>>>(xb, wihb, bias, gx);

    for (int t = 0; t < T_; ++t) {
        lstm_step<<<256, 256, 0, stream>>>(
            hbuf + (size_t)(t & 1) * BH,
            whhb,
            gx + (size_t)t * B_ * G_,
            cT,
            ys + (size_t)t * BH,
            hbuf + (size_t)((t + 1) & 1) * BH);
    }
    hipMemcpyAsync(hT, ys + (size_t)(T_ - 1) * BH, (size_t)BH * sizeof(float), hipMemcpyDeviceToDevice, stream);
}